// Round 13
// baseline (59.349 us; speedup 1.0000x reference)
//
#include <hip/hip_runtime.h>
#include <hip/hip_bf16.h>

#define BB 8
#define HH 64
#define WW 64
#define DD 128
#define NH 4
#define HD 32
#define KS 7
#define TS 8
#define HALO 14   // TS + KS - 1

typedef __attribute__((ext_vector_type(8))) short short8v;   // 8 bf16
typedef __attribute__((ext_vector_type(4))) short short4v;   // 4 bf16
typedef __attribute__((ext_vector_type(4))) float f32x4;
typedef unsigned short bf16_t;

__device__ inline bf16_t f2bf(float f) {
  __hip_bfloat16 h = __float2bfloat16(f);
  return *reinterpret_cast<bf16_t*>(&h);
}

// ---------------------------------------------------------------------------
// Kernel 0: one-shot weight conversion fp32 -> bf16 (weights are re-read by
// 500-1000 blocks; convert once, halve their bytes, delete inline cvts).
// 49152 + 16384 floats = 16384 float4 chunks.
// ---------------------------------------------------------------------------
__global__ __launch_bounds__(256) void convert_w(
    const float* __restrict__ wq, const float* __restrict__ wp,
    bf16_t* __restrict__ wqb, bf16_t* __restrict__ wpb) {
  const int chunk = blockIdx.x * 256 + threadIdx.x;   // 0..16383
  if (chunk < 12288) {
    float4 t = *(const float4*)(wq + chunk * 4);
    short4v s = {(short)f2bf(t.x), (short)f2bf(t.y), (short)f2bf(t.z), (short)f2bf(t.w)};
    *(short4v*)(wqb + chunk * 4) = s;
  } else {
    const int c2 = chunk - 12288;
    float4 t = *(const float4*)(wp + c2 * 4);
    short4v s = {(short)f2bf(t.x), (short)f2bf(t.y), (short)f2bf(t.z), (short)f2bf(t.w)};
    *(short4v*)(wpb + c2 * 4) = s;
  }
}

// ---------------------------------------------------------------------------
// GEMM #1 v2: qkv.  64-row tiles -> grid (512,3); LDS = 16 KB (A-tile only,
// reused as C-tile).  B-fragments read direct from bf16 weights (L1/L2-hot).
// Occupancy 2 -> ~6 blocks/CU.
// ---------------------------------------------------------------------------
__global__ __launch_bounds__(256) void qkv_mfma(
    const float* __restrict__ x, const bf16_t* __restrict__ wqb,
    const float* __restrict__ bqkv,
    bf16_t* __restrict__ q, bf16_t* __restrict__ k, bf16_t* __restrict__ v) {
  __shared__ __align__(16) short smA[64 * 128];   // 16 KB, reused as C
  const int tid = threadIdx.x;
  const int m_tile = blockIdx.x;   // 0..511 (64-row tiles)
  const int n_tile = blockIdx.y;   // 0..2  (0=q 1=k 2=v)

  const float* Ab = x + (size_t)m_tile * 64 * 128;
#pragma unroll
  for (int i = 0; i < 4; i++) {
    int idx = tid + i * 256;      // 0..1023: 64 rows x 16 chunks of 8
    int r = idx >> 4, p = idx & 15;
    const float* ap = Ab + r * 128 + p * 8;
    float4 a0 = *(const float4*)ap;
    float4 a1 = *(const float4*)(ap + 4);
    short8v s;
    s[0] = f2bf(a0.x); s[1] = f2bf(a0.y); s[2] = f2bf(a0.z); s[3] = f2bf(a0.w);
    s[4] = f2bf(a1.x); s[5] = f2bf(a1.y); s[6] = f2bf(a1.z); s[7] = f2bf(a1.w);
    *(short8v*)((char*)smA + ((r * 256 + p * 16) ^ ((r & 7) << 4))) = s;
  }
  __syncthreads();

  const int lane = tid & 63, wid = tid >> 6;
  const int wm = wid >> 1, wn = wid & 1;
  const int l15 = lane & 15, l4 = lane >> 4;

  f32x4 acc[2][4] = {};
  const int rowA0 = wm * 32 + l15;
  const int swzA = (rowA0 & 7) << 4;
  const bf16_t* wb = wqb + (size_t)(n_tile * 128) * 128;

#pragma unroll
  for (int ks = 0; ks < 4; ks++) {
    const int cb = ks * 64 + l4 * 16;   // byte col in LDS
    const int k0 = ks * 32 + l4 * 8;    // element col in weights
    short8v a[2], b[4];
#pragma unroll
    for (int mi = 0; mi < 2; mi++)
      a[mi] = *(const short8v*)((const char*)smA +
                ((((rowA0 + mi * 16) * 256) + cb) ^ swzA));
#pragma unroll
    for (int nj = 0; nj < 4; nj++) {
      const int rowB = wn * 64 + nj * 16 + l15;
      b[nj] = *(const short8v*)(wb + (size_t)rowB * 128 + k0);
    }
#pragma unroll
    for (int mi = 0; mi < 2; mi++)
#pragma unroll
      for (int nj = 0; nj < 4; nj++)
        acc[mi][nj] = __builtin_amdgcn_mfma_f32_16x16x32_bf16(a[mi], b[nj], acc[mi][nj], 0, 0, 0);
  }

  // ---- epilogue: bias+scale -> bf16 C-tile (overlays smA) -> coalesced out
  __syncthreads();
  short* smC = smA;   // [64 m][128 n] bf16, swz ((m&7)<<4)
  const float qscale = 0.17677669529663687f;  // 1/sqrt(32)
  const float sc = (n_tile == 0) ? qscale : 1.f;
#pragma unroll
  for (int nj = 0; nj < 4; nj++) {
    const int n_local = wn * 64 + nj * 16 + l15;
    const float bias = bqkv[n_tile * 128 + n_local];
#pragma unroll
    for (int mi = 0; mi < 2; mi++) {
#pragma unroll
      for (int r = 0; r < 4; r++) {
        const int m = wm * 32 + mi * 16 + l4 * 4 + r;
        *(bf16_t*)((char*)smC + ((m * 256 + n_local * 2) ^ ((m & 7) << 4))) =
            f2bf((acc[mi][nj][r] + bias) * sc);
      }
    }
  }
  __syncthreads();

  const int bblk = m_tile >> 6;    // 64 tiles of 64 rows per batch
  bf16_t* outp = (n_tile == 0) ? q : ((n_tile == 1) ? k : v);
#pragma unroll
  for (int i = 0; i < 4; i++) {
    const int idx = i * 256 + tid;         // 0..1023
    const int h = idx >> 8;                // head plane 0..3
    const int rem = idx & 255;
    const int m = rem >> 2, c = rem & 3;   // pixel row (0..63), 16B chunk
    short8v t8 = *(const short8v*)((const char*)smC +
        ((m * 256 + h * 64 + c * 16) ^ ((m & 7) << 4)));
    const int pix = (m_tile * 64 + m) & 4095;
    *(short8v*)(outp + ((size_t)(bblk * 4 + h)) * 131072 + (size_t)pix * 32 + c * 8) = t8;
  }
}

// ---------------------------------------------------------------------------
// Kernel 2: MFMA neighborhood attention, K-LDS-free (round-10/12 structure,
// unchanged for clean attribution).
// ---------------------------------------------------------------------------
__global__ __launch_bounds__(256) void attn_mfma(
    const bf16_t* __restrict__ q, const bf16_t* __restrict__ k,
    const bf16_t* __restrict__ v, bf16_t* __restrict__ ao) {
  // vtb: [32 d][512 B]  swz ((d&7)<<4), cols = 224 pos + 32 pad
  __shared__ __align__(16) char vtb[16384];

  const int tile = blockIdx.x;
  const int tx = tile >> 3, ty = tile & 7;
  const int head = blockIdx.y, bb = blockIdx.z;
  const size_t bh = ((size_t)bb * NH + head) * 4096;
  const bf16_t* kb = k + bh * HD;
  const bf16_t* vb = v + bh * HD;
  const bf16_t* qb = q + bh * HD;
  const int rstart = min(max(tx * TS - 3, 0), HH - HALO);
  const int cstart = min(max(ty * TS - 3, 0), WW - HALO);
  const int tid = threadIdx.x;
  const int lane = tid & 63, wid = tid >> 6;
  const int l15 = lane & 15, h4 = lane >> 4;

  short8v qf;
  int qx, qy;
  {
    const int pit = wid * 16 + l15;
    qx = tx * TS + (pit >> 3);
    qy = ty * TS + (pit & 7);
    qf = *(const short8v*)(qb + ((size_t)(qx * WW + qy)) * HD + h4 * 8);
  }
  const int wx0 = min(max(qx - 3, 0), HH - KS) - rstart;
  const int wy0 = min(max(qy - 3, 0), WW - KS) - cstart;

  const int x0 = tx * TS + wid * 2;
  const int w0 = min(max(x0 - 3, 0), HH - KS) - rstart;
  const int base = min(w0 & ~1, 4);

  short4v vl[4][2];
#pragma unroll
  for (int t = 0; t < 4; t++) {
    const int idx = tid + t * 256;
    if (idx < 784) {
      const int pp = idx >> 3, c = idx & 7;
      const int pr = pp / 7, pc2 = (pp % 7) * 2;
      const size_t g = ((size_t)((rstart + pr) * WW + (cstart + pc2))) * HD + c * 4;
      vl[t][0] = *(const short4v*)(vb + g);
      vl[t][1] = *(const short4v*)(vb + g + HD);
    }
  }

  f32x4 acc[10];
  const f32x4 zf = {0.f, 0.f, 0.f, 0.f};
  const int kcol = cstart + min(l15, 13);
#pragma unroll
  for (int ch = 0; ch < 2; ch++) {
    short8v kf[5];
#pragma unroll
    for (int i = 0; i < 5; i++) {
      const int pr = rstart + base + ch * 5 + i;
      kf[i] = *(const short8v*)(kb + ((size_t)(pr * WW + kcol)) * HD + h4 * 8);
    }
    __builtin_amdgcn_s_setprio(1);
#pragma unroll
    for (int i = 0; i < 5; i++)
      acc[ch * 5 + i] = __builtin_amdgcn_mfma_f32_16x16x32_bf16(kf[i], qf, zf, 0, 0, 0);
    __builtin_amdgcn_s_setprio(0);
  }

#pragma unroll
  for (int t = 0; t < 4; t++) {
    const int idx = tid + t * 256;
    if (idx < 784) {
      const int pp = idx >> 3, c = idx & 7;
      const int pr = pp / 7, pc2 = (pp % 7) * 2;
      const int pos0 = ((pr >> 1) << 5) + ((pc2 >> 2) << 3) + ((pr & 1) << 2) + (pc2 & 3);
#pragma unroll
      for (int j = 0; j < 4; j++) {
        const int d = c * 4 + j;
        const unsigned pk2 = (unsigned)(unsigned short)vl[t][0][j] |
                             ((unsigned)(unsigned short)vl[t][1][j] << 16);
        *(unsigned*)(vtb + ((d * 512 + pos0 * 2) ^ ((d & 7) << 4))) = pk2;
      }
    }
  }
  for (int idx = tid; idx < 512; idx += 256) {
    const int d = idx >> 4, pr = idx & 15;
    if (pr < 14) {
      const int pos = ((pr >> 1) << 5) + 24 + ((pr & 1) << 2) + 2;
      *(unsigned*)(vtb + ((d * 512 + pos * 2) ^ ((d & 7) << 4))) = 0u;
    }
  }
  __syncthreads();

  bool cv[4];
#pragma unroll
  for (int r = 0; r < 4; r++) cv[r] = ((unsigned)(h4 * 4 + r - wy0) < 7u);
  float sum = 0.f;
#pragma unroll
  for (int nt = 0; nt < 10; nt++) {
    const bool rv = ((unsigned)(base + nt - wx0) < 7u);
#pragma unroll
    for (int r = 0; r < 4; r++) {
      const float p = (rv && cv[r]) ? __expf(acc[nt][r]) : 0.f;
      acc[nt][r] = p;
      sum += p;
    }
  }
  sum += __shfl_xor(sum, 16);
  sum += __shfl_xor(sum, 32);
  const float inv = 1.f / sum;

  f32x4 o0 = zf, o1 = zf;
  const int swzv = (l15 & 7) << 4;
  const int cbase = (base >> 1) * 64;
  __builtin_amdgcn_s_setprio(1);
#pragma unroll
  for (int kc = 0; kc < 5; kc++) {
    union { unsigned u[4]; short8v s; } pa;
    pa.u[0] = (unsigned)f2bf(acc[2 * kc][0] * inv) |
              ((unsigned)f2bf(acc[2 * kc][1] * inv) << 16);
    pa.u[1] = (unsigned)f2bf(acc[2 * kc][2] * inv) |
              ((unsigned)f2bf(acc[2 * kc][3] * inv) << 16);
    pa.u[2] = (unsigned)f2bf(acc[2 * kc + 1][0] * inv) |
              ((unsigned)f2bf(acc[2 * kc + 1][1] * inv) << 16);
    pa.u[3] = (unsigned)f2bf(acc[2 * kc + 1][2] * inv) |
              ((unsigned)f2bf(acc[2 * kc + 1][3] * inv) << 16);
    const int boff = cbase + kc * 64 + h4 * 16;
    short8v vb0 = *(const short8v*)(vtb + ((l15 * 512 + boff) ^ swzv));
    short8v vb1 = *(const short8v*)(vtb + (((l15 + 16) * 512 + boff) ^ swzv));
    o0 = __builtin_amdgcn_mfma_f32_16x16x32_bf16(pa.s, vb0, o0, 0, 0, 0);
    o1 = __builtin_amdgcn_mfma_f32_16x16x32_bf16(pa.s, vb1, o1, 0, 0, 0);
  }
  __builtin_amdgcn_s_setprio(0);

#pragma unroll
  for (int r = 0; r < 4; r++) {
    const int pit = wid * 16 + h4 * 4 + r;
    const int x = tx * TS + (pit >> 3), y = ty * TS + (pit & 7);
    bf16_t* op = ao + ((size_t)bb * 4096 + x * WW + y) * DD + head * HD;
    op[l15]      = (bf16_t)f2bf(o0[r]);
    op[l15 + 16] = (bf16_t)f2bf(o1[r]);
  }
}

// ---------------------------------------------------------------------------
// GEMM #2 v2: proj.  32-row tiles -> grid 1024; LDS 16 KB (8 KB A overlaid
// by 16 KB fp32 C).  B direct from bf16 weights.  Occupancy 1 -> ~4 blocks/CU.
// ---------------------------------------------------------------------------
__global__ __launch_bounds__(256) void proj_mfma(
    const bf16_t* __restrict__ aob, const bf16_t* __restrict__ wpb,
    const float* __restrict__ bp, float* __restrict__ out) {
  __shared__ __align__(16) char plds[16384];   // A: first 8 KB; C: all 16 KB
  short* smA = (short*)plds;
  const int tid = threadIdx.x;
  const int m_tile = blockIdx.x;   // 0..1023 (32-row tiles)

  const bf16_t* Ab = aob + (size_t)m_tile * 32 * 128;
#pragma unroll
  for (int i = 0; i < 2; i++) {
    int idx = tid + i * 256;      // 0..511: 32 rows x 16 chunks
    int r = idx >> 4, p = idx & 15;
    short8v s = *(const short8v*)(Ab + r * 128 + p * 8);
    *(short8v*)((char*)smA + ((r * 256 + p * 16) ^ ((r & 7) << 4))) = s;
  }
  __syncthreads();

  const int lane = tid & 63, wid = tid >> 6;
  const int wm = wid >> 1, wn = wid & 1;
  const int l15 = lane & 15, l4 = lane >> 4;

  f32x4 acc[4] = {};
  const int rowA0 = wm * 16 + l15;
  const int swzA = (rowA0 & 7) << 4;

#pragma unroll
  for (int ks = 0; ks < 4; ks++) {
    const int cb = ks * 64 + l4 * 16;
    const int k0 = ks * 32 + l4 * 8;
    short8v a = *(const short8v*)((const char*)smA + (((rowA0 * 256) + cb) ^ swzA));
    short8v b[4];
#pragma unroll
    for (int nj = 0; nj < 4; nj++) {
      const int rowB = wn * 64 + nj * 16 + l15;
      b[nj] = *(const short8v*)(wpb + (size_t)rowB * 128 + k0);
    }
#pragma unroll
    for (int nj = 0; nj < 4; nj++)
      acc[nj] = __builtin_amdgcn_mfma_f32_16x16x32_bf16(a, b[nj], acc[nj], 0, 0, 0);
  }

  // ---- epilogue: bias -> fp32 C-tile (overlays plds) -> coalesced float4
  __syncthreads();
#pragma unroll
  for (int nj = 0; nj < 4; nj++) {
    const int n = wn * 64 + nj * 16 + l15;
    const float bias = bp[n];
#pragma unroll
    for (int r = 0; r < 4; r++) {
      const int m = wm * 16 + l4 * 4 + r;
      *(float*)(plds + ((m * 512 + n * 4) ^ ((m & 7) << 5))) = acc[nj][r] + bias;
    }
  }
  __syncthreads();

#pragma unroll
  for (int i = 0; i < 4; i++) {
    const int idx = i * 256 + tid;         // 0..1023
    const int m = idx >> 5, c = idx & 31;  // row (0..31), float4 chunk
    float4 t = *(const float4*)(plds + ((m * 512 + c * 16) ^ ((m & 7) << 5)));
    *(float4*)(out + (size_t)(m_tile * 32 + m) * DD + c * 4) = t;
  }
}

// ---------------------------------------------------------------------------
extern "C" void kernel_launch(void* const* d_in, const int* in_sizes, int n_in,
                              void* d_out, int out_size, void* d_ws, size_t ws_size,
                              hipStream_t stream) {
  const float* x      = (const float*)d_in[0];
  const float* w_qkv  = (const float*)d_in[1];
  const float* b_qkv  = (const float*)d_in[2];
  const float* w_proj = (const float*)d_in[3];
  const float* b_proj = (const float*)d_in[4];
  float* out = (float*)d_out;

  const size_t per = (size_t)BB * NH * HH * WW * HD;  // 4,194,304 elements
  bf16_t* q   = (bf16_t*)d_ws;
  bf16_t* k   = q + per;
  bf16_t* v   = k + per;
  bf16_t* ao  = v + per;          // 32 MB
  bf16_t* wqb = ao + per;         // 49152 bf16
  bf16_t* wpb = wqb + 49152;      // 16384 bf16

  convert_w<<<dim3(64), dim3(256), 0, stream>>>(w_qkv, w_proj, wqb, wpb);
  qkv_mfma<<<dim3(512, 3), dim3(256), 0, stream>>>(x, wqb, b_qkv, q, k, v);
  attn_mfma<<<dim3(64, NH, BB), dim3(256), 0, stream>>>(q, k, v, ao);
  proj_mfma<<<dim3(1024), dim3(256), 0, stream>>>(ao, wpb, b_proj, out);
}

// Round 14
// 41.082 us; speedup vs baseline: 1.4447x; 1.4447x over previous
//
#include <hip/hip_runtime.h>
#include <hip/hip_bf16.h>

#define BB 8
#define HH 64
#define WW 64
#define DD 128
#define NH 4
#define HD 32
#define KS 7
#define TS 8
#define HALO 14   // TS + KS - 1

typedef __attribute__((ext_vector_type(8))) short short8v;   // 8 bf16
typedef __attribute__((ext_vector_type(4))) short short4v;   // 4 bf16
typedef __attribute__((ext_vector_type(4))) float f32x4;
typedef unsigned short bf16_t;

__device__ inline bf16_t f2bf(float f) {
  __hip_bfloat16 h = __float2bfloat16(f);
  return *reinterpret_cast<bf16_t*>(&h);
}

// ---------------------------------------------------------------------------
// GEMM #1 v3: qkv.  64-row A-tiles (grid 512x3), B LDS-staged (coalesced,
// conflict-free — the R13 direct-global B was a 16-way gather, reverted).
// LDS = 16 KB A + 32 KB B = 48 KB -> 3 blocks/CU (was 2 at 128-tiles).
// ---------------------------------------------------------------------------
__global__ __launch_bounds__(256) void qkv_mfma(
    const float* __restrict__ x, const float* __restrict__ w,
    const float* __restrict__ bqkv,
    bf16_t* __restrict__ q, bf16_t* __restrict__ k, bf16_t* __restrict__ v) {
  __shared__ __align__(16) short smA[64 * 128];    // 16 KB, reused as C
  __shared__ __align__(16) short smB[128 * 128];   // 32 KB
  const int tid = threadIdx.x;
  const int m_tile = blockIdx.x;   // 0..511 (64-row tiles)
  const int n_tile = blockIdx.y;   // 0..2  (0=q 1=k 2=v)

  const float* Ab = x + (size_t)m_tile * 64 * 128;
  const float* Bb = w + (size_t)n_tile * 128 * 128;
#pragma unroll
  for (int i = 0; i < 4; i++) {
    int idx = tid + i * 256;      // 0..1023: 64 rows x 16 chunks
    int r = idx >> 4, p = idx & 15;
    const float* ap = Ab + r * 128 + p * 8;
    float4 a0 = *(const float4*)ap;
    float4 a1 = *(const float4*)(ap + 4);
    short8v s;
    s[0] = f2bf(a0.x); s[1] = f2bf(a0.y); s[2] = f2bf(a0.z); s[3] = f2bf(a0.w);
    s[4] = f2bf(a1.x); s[5] = f2bf(a1.y); s[6] = f2bf(a1.z); s[7] = f2bf(a1.w);
    *(short8v*)((char*)smA + ((r * 256 + p * 16) ^ ((r & 7) << 4))) = s;
  }
#pragma unroll
  for (int i = 0; i < 8; i++) {
    int idx = tid + i * 256;      // 0..2047: 128 rows x 16 chunks
    int r = idx >> 4, p = idx & 15;
    const float* bp_ = Bb + r * 128 + p * 8;
    float4 b0 = *(const float4*)bp_;
    float4 b1 = *(const float4*)(bp_ + 4);
    short8v t;
    t[0] = f2bf(b0.x); t[1] = f2bf(b0.y); t[2] = f2bf(b0.z); t[3] = f2bf(b0.w);
    t[4] = f2bf(b1.x); t[5] = f2bf(b1.y); t[6] = f2bf(b1.z); t[7] = f2bf(b1.w);
    *(short8v*)((char*)smB + ((r * 256 + p * 16) ^ ((r & 7) << 4))) = t;
  }
  __syncthreads();

  const int lane = tid & 63, wid = tid >> 6;
  const int wm = wid >> 1, wn = wid & 1;
  const int l15 = lane & 15, l4 = lane >> 4;

  f32x4 acc[2][4] = {};
  const int rowA0 = wm * 32 + l15;
  const int rowB0 = wn * 64 + l15;
  const int swzA = (rowA0 & 7) << 4;
  const int swzB = (rowB0 & 7) << 4;

#pragma unroll
  for (int ks = 0; ks < 4; ks++) {
    const int cb = ks * 64 + l4 * 16;
    short8v a[2], b[4];
#pragma unroll
    for (int mi = 0; mi < 2; mi++)
      a[mi] = *(const short8v*)((const char*)smA +
                ((((rowA0 + mi * 16) * 256) + cb) ^ swzA));
#pragma unroll
    for (int nj = 0; nj < 4; nj++)
      b[nj] = *(const short8v*)((const char*)smB +
                ((((rowB0 + nj * 16) * 256) + cb) ^ swzB));
#pragma unroll
    for (int mi = 0; mi < 2; mi++)
#pragma unroll
      for (int nj = 0; nj < 4; nj++)
        acc[mi][nj] = __builtin_amdgcn_mfma_f32_16x16x32_bf16(a[mi], b[nj], acc[mi][nj], 0, 0, 0);
  }

  // ---- epilogue: bias+scale -> bf16 C-tile (overlays smA) -> coalesced out
  __syncthreads();
  short* smC = smA;   // [64 m][128 n] bf16, swz ((m&7)<<4)
  const float qscale = 0.17677669529663687f;  // 1/sqrt(32)
  const float sc = (n_tile == 0) ? qscale : 1.f;
#pragma unroll
  for (int nj = 0; nj < 4; nj++) {
    const int n_local = wn * 64 + nj * 16 + l15;
    const float bias = bqkv[n_tile * 128 + n_local];
#pragma unroll
    for (int mi = 0; mi < 2; mi++) {
#pragma unroll
      for (int r = 0; r < 4; r++) {
        const int m = wm * 32 + mi * 16 + l4 * 4 + r;
        *(bf16_t*)((char*)smC + ((m * 256 + n_local * 2) ^ ((m & 7) << 4))) =
            f2bf((acc[mi][nj][r] + bias) * sc);
      }
    }
  }
  __syncthreads();

  const int bblk = m_tile >> 6;    // 64 tiles of 64 rows per batch
  bf16_t* outp = (n_tile == 0) ? q : ((n_tile == 1) ? k : v);
#pragma unroll
  for (int i = 0; i < 4; i++) {
    const int idx = i * 256 + tid;         // 0..1023
    const int h = idx >> 8;                // head plane 0..3
    const int rem = idx & 255;
    const int m = rem >> 2, c = rem & 3;   // pixel row (0..63), 16B chunk
    short8v t8 = *(const short8v*)((const char*)smC +
        ((m * 256 + h * 64 + c * 16) ^ ((m & 7) << 4)));
    const int pix = (m_tile * 64 + m) & 4095;
    *(short8v*)(outp + ((size_t)(bblk * 4 + h)) * 131072 + (size_t)pix * 32 + c * 8) = t8;
  }
}

// ---------------------------------------------------------------------------
// Kernel 2: MFMA neighborhood attention, K-LDS-free (unchanged from R12).
// ---------------------------------------------------------------------------
__global__ __launch_bounds__(256) void attn_mfma(
    const bf16_t* __restrict__ q, const bf16_t* __restrict__ k,
    const bf16_t* __restrict__ v, bf16_t* __restrict__ ao) {
  // vtb: [32 d][512 B]  swz ((d&7)<<4), cols = 224 pos + 32 pad
  __shared__ __align__(16) char vtb[16384];

  const int tile = blockIdx.x;
  const int tx = tile >> 3, ty = tile & 7;
  const int head = blockIdx.y, bb = blockIdx.z;
  const size_t bh = ((size_t)bb * NH + head) * 4096;
  const bf16_t* kb = k + bh * HD;
  const bf16_t* vb = v + bh * HD;
  const bf16_t* qb = q + bh * HD;
  const int rstart = min(max(tx * TS - 3, 0), HH - HALO);
  const int cstart = min(max(ty * TS - 3, 0), WW - HALO);
  const int tid = threadIdx.x;
  const int lane = tid & 63, wid = tid >> 6;
  const int l15 = lane & 15, h4 = lane >> 4;

  short8v qf;
  int qx, qy;
  {
    const int pit = wid * 16 + l15;
    qx = tx * TS + (pit >> 3);
    qy = ty * TS + (pit & 7);
    qf = *(const short8v*)(qb + ((size_t)(qx * WW + qy)) * HD + h4 * 8);
  }
  const int wx0 = min(max(qx - 3, 0), HH - KS) - rstart;
  const int wy0 = min(max(qy - 3, 0), WW - KS) - cstart;

  const int x0 = tx * TS + wid * 2;
  const int w0 = min(max(x0 - 3, 0), HH - KS) - rstart;
  const int base = min(w0 & ~1, 4);

  short4v vl[4][2];
#pragma unroll
  for (int t = 0; t < 4; t++) {
    const int idx = tid + t * 256;
    if (idx < 784) {
      const int pp = idx >> 3, c = idx & 7;
      const int pr = pp / 7, pc2 = (pp % 7) * 2;
      const size_t g = ((size_t)((rstart + pr) * WW + (cstart + pc2))) * HD + c * 4;
      vl[t][0] = *(const short4v*)(vb + g);
      vl[t][1] = *(const short4v*)(vb + g + HD);
    }
  }

  f32x4 acc[10];
  const f32x4 zf = {0.f, 0.f, 0.f, 0.f};
  const int kcol = cstart + min(l15, 13);
#pragma unroll
  for (int ch = 0; ch < 2; ch++) {
    short8v kf[5];
#pragma unroll
    for (int i = 0; i < 5; i++) {
      const int pr = rstart + base + ch * 5 + i;
      kf[i] = *(const short8v*)(kb + ((size_t)(pr * WW + kcol)) * HD + h4 * 8);
    }
    __builtin_amdgcn_s_setprio(1);
#pragma unroll
    for (int i = 0; i < 5; i++)
      acc[ch * 5 + i] = __builtin_amdgcn_mfma_f32_16x16x32_bf16(kf[i], qf, zf, 0, 0, 0);
    __builtin_amdgcn_s_setprio(0);
  }

#pragma unroll
  for (int t = 0; t < 4; t++) {
    const int idx = tid + t * 256;
    if (idx < 784) {
      const int pp = idx >> 3, c = idx & 7;
      const int pr = pp / 7, pc2 = (pp % 7) * 2;
      const int pos0 = ((pr >> 1) << 5) + ((pc2 >> 2) << 3) + ((pr & 1) << 2) + (pc2 & 3);
#pragma unroll
      for (int j = 0; j < 4; j++) {
        const int d = c * 4 + j;
        const unsigned pk2 = (unsigned)(unsigned short)vl[t][0][j] |
                             ((unsigned)(unsigned short)vl[t][1][j] << 16);
        *(unsigned*)(vtb + ((d * 512 + pos0 * 2) ^ ((d & 7) << 4))) = pk2;
      }
    }
  }
  for (int idx = tid; idx < 512; idx += 256) {
    const int d = idx >> 4, pr = idx & 15;
    if (pr < 14) {
      const int pos = ((pr >> 1) << 5) + 24 + ((pr & 1) << 2) + 2;
      *(unsigned*)(vtb + ((d * 512 + pos * 2) ^ ((d & 7) << 4))) = 0u;
    }
  }
  __syncthreads();

  bool cv[4];
#pragma unroll
  for (int r = 0; r < 4; r++) cv[r] = ((unsigned)(h4 * 4 + r - wy0) < 7u);
  float sum = 0.f;
#pragma unroll
  for (int nt = 0; nt < 10; nt++) {
    const bool rv = ((unsigned)(base + nt - wx0) < 7u);
#pragma unroll
    for (int r = 0; r < 4; r++) {
      const float p = (rv && cv[r]) ? __expf(acc[nt][r]) : 0.f;
      acc[nt][r] = p;
      sum += p;
    }
  }
  sum += __shfl_xor(sum, 16);
  sum += __shfl_xor(sum, 32);
  const float inv = 1.f / sum;

  f32x4 o0 = zf, o1 = zf;
  const int swzv = (l15 & 7) << 4;
  const int cbase = (base >> 1) * 64;
  __builtin_amdgcn_s_setprio(1);
#pragma unroll
  for (int kc = 0; kc < 5; kc++) {
    union { unsigned u[4]; short8v s; } pa;
    pa.u[0] = (unsigned)f2bf(acc[2 * kc][0] * inv) |
              ((unsigned)f2bf(acc[2 * kc][1] * inv) << 16);
    pa.u[1] = (unsigned)f2bf(acc[2 * kc][2] * inv) |
              ((unsigned)f2bf(acc[2 * kc][3] * inv) << 16);
    pa.u[2] = (unsigned)f2bf(acc[2 * kc + 1][0] * inv) |
              ((unsigned)f2bf(acc[2 * kc + 1][1] * inv) << 16);
    pa.u[3] = (unsigned)f2bf(acc[2 * kc + 1][2] * inv) |
              ((unsigned)f2bf(acc[2 * kc + 1][3] * inv) << 16);
    const int boff = cbase + kc * 64 + h4 * 16;
    short8v vb0 = *(const short8v*)(vtb + ((l15 * 512 + boff) ^ swzv));
    short8v vb1 = *(const short8v*)(vtb + (((l15 + 16) * 512 + boff) ^ swzv));
    o0 = __builtin_amdgcn_mfma_f32_16x16x32_bf16(pa.s, vb0, o0, 0, 0, 0);
    o1 = __builtin_amdgcn_mfma_f32_16x16x32_bf16(pa.s, vb1, o1, 0, 0, 0);
  }
  __builtin_amdgcn_s_setprio(0);

#pragma unroll
  for (int r = 0; r < 4; r++) {
    const int pit = wid * 16 + h4 * 4 + r;
    const int x = tx * TS + (pit >> 3), y = ty * TS + (pit & 7);
    bf16_t* op = ao + ((size_t)bb * 4096 + x * WW + y) * DD + head * HD;
    op[l15]      = (bf16_t)f2bf(o0[r]);
    op[l15 + 16] = (bf16_t)f2bf(o1[r]);
  }
}

// ---------------------------------------------------------------------------
// GEMM #2 v3: proj.  64-row A-tiles (grid 512), B LDS-staged.
// LDS = 16 KB A + 32 KB B = 48 KB -> 3 blocks/CU (was 1 at 128-tiles!).
// fp32 C-tile (32 KB) overlays smB for the coalesced writeout.
// ---------------------------------------------------------------------------
__global__ __launch_bounds__(256) void proj_mfma(
    const bf16_t* __restrict__ aob, const float* __restrict__ wp,
    const float* __restrict__ bp, float* __restrict__ out) {
  __shared__ __align__(16) char plds[49152];
  short* smA = (short*)plds;              // 16 KB [64][128] bf16
  short* smB = (short*)(plds + 16384);    // 32 KB [128][128] bf16; C overlays
  const int tid = threadIdx.x;
  const int m_tile = blockIdx.x;   // 0..511 (64-row tiles)

  const bf16_t* Ab = aob + (size_t)m_tile * 64 * 128;
#pragma unroll
  for (int i = 0; i < 4; i++) {
    int idx = tid + i * 256;      // 0..1023
    int r = idx >> 4, p = idx & 15;
    short8v s = *(const short8v*)(Ab + r * 128 + p * 8);
    *(short8v*)((char*)smA + ((r * 256 + p * 16) ^ ((r & 7) << 4))) = s;
  }
#pragma unroll
  for (int i = 0; i < 8; i++) {
    int idx = tid + i * 256;      // 0..2047
    int r = idx >> 4, p = idx & 15;
    const float* bp_ = wp + r * 128 + p * 8;
    float4 b0 = *(const float4*)bp_;
    float4 b1 = *(const float4*)(bp_ + 4);
    short8v t;
    t[0] = f2bf(b0.x); t[1] = f2bf(b0.y); t[2] = f2bf(b0.z); t[3] = f2bf(b0.w);
    t[4] = f2bf(b1.x); t[5] = f2bf(b1.y); t[6] = f2bf(b1.z); t[7] = f2bf(b1.w);
    *(short8v*)((char*)smB + ((r * 256 + p * 16) ^ ((r & 7) << 4))) = t;
  }
  __syncthreads();

  const int lane = tid & 63, wid = tid >> 6;
  const int wm = wid >> 1, wn = wid & 1;
  const int l15 = lane & 15, l4 = lane >> 4;

  f32x4 acc[2][4] = {};
  const int rowA0 = wm * 32 + l15;
  const int rowB0 = wn * 64 + l15;
  const int swzA = (rowA0 & 7) << 4;
  const int swzB = (rowB0 & 7) << 4;

#pragma unroll
  for (int ks = 0; ks < 4; ks++) {
    const int cb = ks * 64 + l4 * 16;
    short8v a[2], b[4];
#pragma unroll
    for (int mi = 0; mi < 2; mi++)
      a[mi] = *(const short8v*)((const char*)smA +
                ((((rowA0 + mi * 16) * 256) + cb) ^ swzA));
#pragma unroll
    for (int nj = 0; nj < 4; nj++)
      b[nj] = *(const short8v*)((const char*)smB +
                ((((rowB0 + nj * 16) * 256) + cb) ^ swzB));
#pragma unroll
    for (int mi = 0; mi < 2; mi++)
#pragma unroll
      for (int nj = 0; nj < 4; nj++)
        acc[mi][nj] = __builtin_amdgcn_mfma_f32_16x16x32_bf16(a[mi], b[nj], acc[mi][nj], 0, 0, 0);
  }

  // ---- epilogue: bias -> fp32 C-tile (overlays smB) -> coalesced float4
  __syncthreads();
  char* smC = plds + 16384;   // [64 m][512 B] fp32, swz ((m&7)<<5)
#pragma unroll
  for (int nj = 0; nj < 4; nj++) {
    const int n = wn * 64 + nj * 16 + l15;
    const float bias = bp[n];
#pragma unroll
    for (int mi = 0; mi < 2; mi++) {
#pragma unroll
      for (int r = 0; r < 4; r++) {
        const int m = wm * 32 + mi * 16 + l4 * 4 + r;
        *(float*)(smC + ((m * 512 + n * 4) ^ ((m & 7) << 5))) = acc[mi][nj][r] + bias;
      }
    }
  }
  __syncthreads();

#pragma unroll
  for (int i = 0; i < 8; i++) {
    const int idx = i * 256 + tid;         // 0..2047
    const int m = idx >> 5, c = idx & 31;  // row (0..63), float4 chunk
    float4 t = *(const float4*)(smC + ((m * 512 + c * 16) ^ ((m & 7) << 5)));
    *(float4*)(out + (size_t)(m_tile * 64 + m) * DD + c * 4) = t;
  }
}

// ---------------------------------------------------------------------------
extern "C" void kernel_launch(void* const* d_in, const int* in_sizes, int n_in,
                              void* d_out, int out_size, void* d_ws, size_t ws_size,
                              hipStream_t stream) {
  const float* x      = (const float*)d_in[0];
  const float* w_qkv  = (const float*)d_in[1];
  const float* b_qkv  = (const float*)d_in[2];
  const float* w_proj = (const float*)d_in[3];
  const float* b_proj = (const float*)d_in[4];
  float* out = (float*)d_out;

  const size_t per = (size_t)BB * NH * HH * WW * HD;  // 4,194,304 elements
  bf16_t* q  = (bf16_t*)d_ws;
  bf16_t* k  = q + per;
  bf16_t* v  = k + per;
  bf16_t* ao = v + per;   // 32 MB bf16 workspace

  qkv_mfma<<<dim3(512, 3), dim3(256), 0, stream>>>(x, w_qkv, b_qkv, q, k, v);
  attn_mfma<<<dim3(64, NH, BB), dim3(256), 0, stream>>>(q, k, v, ao);
  proj_mfma<<<dim3(512), dim3(256), 0, stream>>>(ao, w_proj, b_proj, out);
}